// Round 10
// baseline (150.892 us; speedup 1.0000x reference)
//
#include <hip/hip_runtime.h>

#define N_NODES 100000
#define N_EDGES 1600000
#define IN_F 256
#define OUT_F 128
#define LDK 40  // padded k-stride (bf16 elems) for LDS tiles

// two-level counting sort params
#define NBUCK 391            // ceil(N_NODES / 256): coarse bucket = dst >> 8
#define NCHUNK 256           // edge chunks
#define CHUNK_E (N_EDGES / NCHUNK)  // 6250
#define NSCAN (NBUCK * NCHUNK)      // 100096 count-matrix entries (mult of 16)
#define SCAN_BLK 4096        // elems per scan1 block
#define NSCAN_BLOCKS ((NSCAN + SCAN_BLK - 1) / SCAN_BLK)  // 25

typedef __attribute__((ext_vector_type(8))) short bf16x8;
typedef __attribute__((ext_vector_type(4))) float f32x4;

__device__ __forceinline__ unsigned short f2bf(float f) {
    unsigned u = __float_as_uint(f);
    unsigned r = u + 0x7fffu + ((u >> 16) & 1u);  // RNE
    return (unsigned short)(r >> 16);
}

// ---------------------------------------------------------------------------
// K1: count (blocks 0..255)  ∥  wtrans (blocks 256..383)
// ---------------------------------------------------------------------------
__global__ __launch_bounds__(256) void count_wtrans_kernel(const int* __restrict__ rowi,
                                                           int* __restrict__ counts,
                                                           const float* __restrict__ w,
                                                           unsigned short* __restrict__ wt) {
    const int tid = threadIdx.x;
    if (blockIdx.x >= NCHUNK) {
        int c = blockIdx.x - NCHUNK;  // 0..127
        wt[c * IN_F + tid] = f2bf(w[tid * OUT_F + c]);
        return;
    }
    __shared__ int hist[NBUCK];
    const int c = blockIdx.x;
    for (int i = tid; i < NBUCK; i += 256) hist[i] = 0;
    __syncthreads();
    const int e0 = c * CHUNK_E;
    for (int i = tid; i < CHUNK_E; i += 256)
        atomicAdd(&hist[rowi[e0 + i] >> 8], 1);
    __syncthreads();
    for (int i = tid; i < NBUCK; i += 256) counts[i * NCHUNK + c] = hist[i];
}

// ---------------------------------------------------------------------------
// K2: scan1 — per-block (4096 elems) exclusive scan in place + block sums.
// ---------------------------------------------------------------------------
__global__ __launch_bounds__(256) void scan1_kernel(int* __restrict__ data,
                                                    int* __restrict__ blocksums,
                                                    int n) {
    __shared__ int sdata[256];
    const int tid = threadIdx.x;
    const int base = blockIdx.x * SCAN_BLK + tid * 16;
    int v[16];
    if (base < n) {
#pragma unroll
        for (int q = 0; q < 4; ++q) {
            int4 t = *reinterpret_cast<const int4*>(&data[base + q * 4]);
            v[q * 4 + 0] = t.x; v[q * 4 + 1] = t.y; v[q * 4 + 2] = t.z; v[q * 4 + 3] = t.w;
        }
    } else {
#pragma unroll
        for (int i = 0; i < 16; ++i) v[i] = 0;
    }
    int pre[16], run = 0;
#pragma unroll
    for (int i = 0; i < 16; ++i) { pre[i] = run; run += v[i]; }
    sdata[tid] = run;
    __syncthreads();
#pragma unroll
    for (int off = 1; off < 256; off <<= 1) {
        int t = (tid >= off) ? sdata[tid - off] : 0;
        __syncthreads();
        sdata[tid] += t;
        __syncthreads();
    }
    int excl = (tid == 0) ? 0 : sdata[tid - 1];
    if (base < n) {
#pragma unroll
        for (int q = 0; q < 4; ++q) {
            int4 t = {excl + pre[q * 4 + 0], excl + pre[q * 4 + 1],
                      excl + pre[q * 4 + 2], excl + pre[q * 4 + 3]};
            *reinterpret_cast<int4*>(&data[base + q * 4]) = t;
        }
    }
    if (tid == 255) blocksums[blockIdx.x] = sdata[255];
}

// ---------------------------------------------------------------------------
// K3: scan2 — single block exclusive scan of nblk (<=256) block sums.
// ---------------------------------------------------------------------------
__global__ __launch_bounds__(256) void scan2_kernel(int* __restrict__ blocksums, int nblk) {
    __shared__ int sdata[256];
    const int tid = threadIdx.x;
    sdata[tid] = (tid < nblk) ? blocksums[tid] : 0;
    __syncthreads();
#pragma unroll
    for (int off = 1; off < 256; off <<= 1) {
        int t = (tid >= off) ? sdata[tid - off] : 0;
        __syncthreads();
        sdata[tid] += t;
        __syncthreads();
    }
    if (tid < nblk) blocksums[tid] = (tid == 0) ? 0 : sdata[tid - 1];
}

// ---------------------------------------------------------------------------
// K4: scatter1 (blocks 0..255)  ∥  gemm (blocks 256..1037)
// gemm is software-pipelined: write tile kt from regs -> issue loads kt+1 ->
// compute kt. All staging addresses hoisted (only +kt*32 varies).
// ---------------------------------------------------------------------------
__global__ __launch_bounds__(256) void gemm_scatter_kernel(const float* __restrict__ x,
                                                           const unsigned short* __restrict__ wt,
                                                           unsigned short* __restrict__ support,
                                                           const int* __restrict__ rowi,
                                                           const int* __restrict__ coli,
                                                           const float* __restrict__ val,
                                                           const int* __restrict__ counts,
                                                           const int* __restrict__ blocksums,
                                                           uint2* __restrict__ tmp) {
    const int tid = threadIdx.x;

    if (blockIdx.x < NCHUNK) {
        // ----- scatter1 -----
        __shared__ int cur[NBUCK];
        const int c = blockIdx.x;
        for (int i = tid; i < NBUCK; i += 256) {
            int j = i * NCHUNK + c;
            cur[i] = counts[j] + blocksums[j >> 12];
        }
        __syncthreads();
        const int e0 = c * CHUNK_E;
        for (int i = tid; i < CHUNK_E; i += 256) {
            int e = e0 + i;
            int dst = rowi[e];
            int b = dst >> 8;
            int pos = atomicAdd(&cur[b], 1);
            tmp[pos] = make_uint2(((unsigned)(dst & 255) << 17) | (unsigned)coli[e],
                                  __float_as_uint(val[e]));
        }
        return;
    }

    // ----- gemm (pipelined) -----
    __shared__ unsigned short xs[128 * LDK];
    __shared__ unsigned short ws[128 * LDK];

    const int lane = tid & 63;
    const int wv = tid >> 6;
    const int wr = (wv >> 1) * 64;
    const int wc = (wv & 1) * 64;
    const int row0 = (blockIdx.x - NCHUNK) * 128;
    const int l15 = lane & 15;
    const int kg = (lane >> 4) * 8;

    // hoisted staging addresses (x: 4 chunks/thread, wt: 2 chunks/thread)
    const float* pxg[4];
    unsigned short* pxl[4];
#pragma unroll
    for (int i = 0; i < 4; ++i) {
        int idx = tid + 256 * i;
        int r = idx >> 3, q = idx & 7;
        int grow = row0 + r;
        if (grow > N_NODES - 1) grow = N_NODES - 1;
        pxg[i] = &x[(size_t)grow * IN_F + q * 4];
        pxl[i] = &xs[r * LDK + q * 4];
    }
    const unsigned short* pwg[2];
    unsigned short* pwl[2];
#pragma unroll
    for (int j = 0; j < 2; ++j) {
        int idx = tid + 256 * j;
        int c = idx >> 2, q = idx & 3;
        pwg[j] = &wt[c * IN_F + q * 8];
        pwl[j] = &ws[c * LDK + q * 8];
    }

    f32x4 acc[4][4];
#pragma unroll
    for (int m = 0; m < 4; ++m)
#pragma unroll
        for (int n = 0; n < 4; ++n) acc[m][n] = (f32x4){0.f, 0.f, 0.f, 0.f};

    // prologue: issue tile-0 loads
    float4 xv[4];
    uint4 wvr[2];
#pragma unroll
    for (int i = 0; i < 4; ++i) xv[i] = *reinterpret_cast<const float4*>(pxg[i]);
#pragma unroll
    for (int j = 0; j < 2; ++j) wvr[j] = *reinterpret_cast<const uint4*>(pwg[j]);

#pragma unroll
    for (int kt = 0; kt < 8; ++kt) {
        __syncthreads();  // previous tile's LDS reads complete
        // write current tile regs -> LDS (convert x to bf16)
#pragma unroll
        for (int i = 0; i < 4; ++i) {
            ushort4 b;
            b.x = f2bf(xv[i].x); b.y = f2bf(xv[i].y);
            b.z = f2bf(xv[i].z); b.w = f2bf(xv[i].w);
            *reinterpret_cast<ushort4*>(pxl[i]) = b;
        }
#pragma unroll
        for (int j = 0; j < 2; ++j)
            *reinterpret_cast<uint4*>(pwl[j]) = wvr[j];

        // issue next tile loads (latency hides under compute below)
        float4 nx[4];
        uint4 nw[2];
        if (kt < 7) {
#pragma unroll
            for (int i = 0; i < 4; ++i)
                nx[i] = *reinterpret_cast<const float4*>(pxg[i] + (kt + 1) * 32);
#pragma unroll
            for (int j = 0; j < 2; ++j)
                nw[j] = *reinterpret_cast<const uint4*>(pwg[j] + (kt + 1) * 32);
        }

        __syncthreads();  // LDS tile ready

        bf16x8 af[4], bfr[4];
#pragma unroll
        for (int m = 0; m < 4; ++m)
            af[m] = *reinterpret_cast<const bf16x8*>(&xs[(wr + m * 16 + l15) * LDK + kg]);
#pragma unroll
        for (int n = 0; n < 4; ++n)
            bfr[n] = *reinterpret_cast<const bf16x8*>(&ws[(wc + n * 16 + l15) * LDK + kg]);
#pragma unroll
        for (int m = 0; m < 4; ++m)
#pragma unroll
            for (int n = 0; n < 4; ++n)
                acc[m][n] = __builtin_amdgcn_mfma_f32_16x16x32_bf16(af[m], bfr[n], acc[m][n], 0, 0, 0);

        if (kt < 7) {
#pragma unroll
            for (int i = 0; i < 4; ++i) xv[i] = nx[i];
#pragma unroll
            for (int j = 0; j < 2; ++j) wvr[j] = nw[j];
        }
    }

#pragma unroll
    for (int m = 0; m < 4; ++m) {
#pragma unroll
        for (int r = 0; r < 4; ++r) {
            int row = row0 + wr + m * 16 + (lane >> 4) * 4 + r;
            if (row < N_NODES) {
#pragma unroll
                for (int n = 0; n < 4; ++n) {
                    support[(size_t)row * OUT_F + wc + n * 16 + l15] = f2bf(acc[m][n][r]);
                }
            }
        }
    }
}

// ---------------------------------------------------------------------------
// K5: fine sort within one 256-node bucket; writes per-node end offsets.
// ---------------------------------------------------------------------------
__global__ __launch_bounds__(256) void fine_kernel(const uint2* __restrict__ tmp,
                                                   const int* __restrict__ counts,
                                                   const int* __restrict__ blocksums,
                                                   uint2* __restrict__ pairs,
                                                   int* __restrict__ offsets) {
    __shared__ int hist[256];
    __shared__ int scanb[256];
    __shared__ int cur[256];
    const int tid = threadIdx.x, b = blockIdx.x;
    int j0 = b * NCHUNK;
    const int start = counts[j0] + blocksums[j0 >> 12];
    int end;
    if (b == NBUCK - 1) end = N_EDGES;
    else {
        int j1 = (b + 1) * NCHUNK;
        end = counts[j1] + blocksums[j1 >> 12];
    }

    hist[tid] = 0;
    __syncthreads();
    for (int i = start + tid; i < end; i += 256)
        atomicAdd(&hist[tmp[i].x >> 17], 1);
    __syncthreads();
    int h = hist[tid];
    scanb[tid] = h;
    __syncthreads();
#pragma unroll
    for (int off = 1; off < 256; off <<= 1) {
        int t = (tid >= off) ? scanb[tid - off] : 0;
        __syncthreads();
        scanb[tid] += t;
        __syncthreads();
    }
    cur[tid] = start + scanb[tid] - h;
    int node = (b << 8) + tid;
    if (node < N_NODES) offsets[node] = start + scanb[tid];
    __syncthreads();
    for (int i = start + tid; i < end; i += 256) {
        uint2 u = tmp[i];
        int dl = u.x >> 17;
        int pos = atomicAdd(&cur[dl], 1);
        pairs[pos] = make_uint2(u.x & 0x1FFFFu, u.y);
    }
}

// ---------------------------------------------------------------------------
// K6: accumulate: one wave64 per node, 4 edge slots x 16 lanes (8 feats each),
// x2 unroll -> 8 gathers in flight per wave. (round-6 proven)
// ---------------------------------------------------------------------------
__global__ __launch_bounds__(256) void accum_kernel(const unsigned short* __restrict__ support,
                                                    const uint2* __restrict__ pairs,
                                                    const int* __restrict__ offsets,
                                                    const float* __restrict__ bias,
                                                    float* __restrict__ out) {
    const int node = blockIdx.x * 4 + (threadIdx.x >> 6);
    const int lane = threadIdx.x & 63;
    const int grp = lane >> 4;   // edge slot 0..3
    const int l16 = lane & 15;   // feats l16*8 .. l16*8+7
    if (node >= N_NODES) return;

    const int start = (node == 0) ? 0 : offsets[node - 1];
    const int end = offsets[node];

    float acc[8];
#pragma unroll
    for (int t = 0; t < 8; ++t) acc[t] = 0.f;

    int j = start + grp;
    for (; j + 4 < end; j += 8) {
        uint2 p0 = pairs[j];
        uint2 p1 = pairs[j + 4];
        uint4 s0 = *reinterpret_cast<const uint4*>(&support[(size_t)p0.x * OUT_F + l16 * 8]);
        uint4 s1 = *reinterpret_cast<const uint4*>(&support[(size_t)p1.x * OUT_F + l16 * 8]);
        float v0 = __uint_as_float(p0.y);
        float v1 = __uint_as_float(p1.y);
        unsigned u0[4] = {s0.x, s0.y, s0.z, s0.w};
        unsigned u1[4] = {s1.x, s1.y, s1.z, s1.w};
#pragma unroll
        for (int q = 0; q < 4; ++q) {
            acc[2 * q + 0] += __uint_as_float(u0[q] << 16) * v0;
            acc[2 * q + 1] += __uint_as_float(u0[q] & 0xffff0000u) * v0;
            acc[2 * q + 0] += __uint_as_float(u1[q] << 16) * v1;
            acc[2 * q + 1] += __uint_as_float(u1[q] & 0xffff0000u) * v1;
        }
    }
    for (; j < end; j += 4) {
        uint2 p0 = pairs[j];
        uint4 s0 = *reinterpret_cast<const uint4*>(&support[(size_t)p0.x * OUT_F + l16 * 8]);
        float v0 = __uint_as_float(p0.y);
        unsigned u0[4] = {s0.x, s0.y, s0.z, s0.w};
#pragma unroll
        for (int q = 0; q < 4; ++q) {
            acc[2 * q + 0] += __uint_as_float(u0[q] << 16) * v0;
            acc[2 * q + 1] += __uint_as_float(u0[q] & 0xffff0000u) * v0;
        }
    }

#pragma unroll
    for (int t = 0; t < 8; ++t) {
        acc[t] += __shfl_xor(acc[t], 16);
        acc[t] += __shfl_xor(acc[t], 32);
    }

    if (grp == 0) {
        float4 b0 = *reinterpret_cast<const float4*>(&bias[l16 * 8]);
        float4 b1 = *reinterpret_cast<const float4*>(&bias[l16 * 8 + 4]);
        f32x4 o0 = {acc[0] + b0.x, acc[1] + b0.y, acc[2] + b0.z, acc[3] + b0.w};
        f32x4 o1 = {acc[4] + b1.x, acc[5] + b1.y, acc[6] + b1.z, acc[7] + b1.w};
        f32x4* op = reinterpret_cast<f32x4*>(&out[(size_t)node * OUT_F + l16 * 8]);
        __builtin_nontemporal_store(o0, op);
        __builtin_nontemporal_store(o1, op + 1);
    }
}

extern "C" void kernel_launch(void* const* d_in, const int* in_sizes, int n_in,
                              void* d_out, int out_size, void* d_ws, size_t ws_size,
                              hipStream_t stream) {
    const float* x       = (const float*)d_in[0];
    const float* weight  = (const float*)d_in[1];
    const float* bias    = (const float*)d_in[2];
    const float* adj_val = (const float*)d_in[3];
    const int*   adj_row = (const int*)d_in[4];
    const int*   adj_col = (const int*)d_in[5];
    float* out = (float*)d_out;

    unsigned short* support = (unsigned short*)d_ws;
    unsigned short* wt = support + (size_t)N_NODES * OUT_F;
    int* counts = (int*)(wt + IN_F * OUT_F);
    int* blocksums = counts + NSCAN;
    int* offsets = blocksums + 32;
    uint2* tmp = (uint2*)(offsets + 100000);
    uint2* pairs = tmp + N_EDGES;

    // K1: count ∥ wtrans
    count_wtrans_kernel<<<NCHUNK + OUT_F, 256, 0, stream>>>(adj_row, counts, weight, wt);
    // K2/K3: scan
    scan1_kernel<<<NSCAN_BLOCKS, 256, 0, stream>>>(counts, blocksums, NSCAN);
    scan2_kernel<<<1, 256, 0, stream>>>(blocksums, NSCAN_BLOCKS);
    // K4: scatter1 ∥ gemm (pipelined)
    gemm_scatter_kernel<<<NCHUNK + (N_NODES + 127) / 128, 256, 0, stream>>>(
        x, wt, support, adj_row, adj_col, adj_val, counts, blocksums, tmp);
    // K5: fine sort per bucket
    fine_kernel<<<NBUCK, 256, 0, stream>>>(tmp, counts, blocksums, pairs, offsets);
    // K6: accumulate per destination node
    accum_kernel<<<(N_NODES + 3) / 4, 256, 0, stream>>>(support, pairs, offsets, bias, out);
}

// Round 11
// 136.671 us; speedup vs baseline: 1.1040x; 1.1040x over previous
//
#include <hip/hip_runtime.h>

#define N_NODES 100000
#define N_EDGES 1600000
#define IN_F 256
#define OUT_F 128
#define LDK 40  // padded k-stride (bf16 elems) for LDS tiles

// two-level counting sort params
#define NBUCK 391            // ceil(N_NODES / 256): coarse bucket = dst >> 8
#define NCHUNK 256           // edge chunks
#define CHUNK_E (N_EDGES / NCHUNK)  // 6250
#define NSCAN (NBUCK * NCHUNK)      // 100096 count-matrix entries (mult of 16)
#define SCAN_BLK 4096        // elems per scan1 block
#define NSCAN_BLOCKS ((NSCAN + SCAN_BLK - 1) / SCAN_BLK)  // 25

#define GEMM_BM 64           // gemm tile rows (small tile -> more blocks/CU)
#define GEMM_BLOCKS ((N_NODES + GEMM_BM - 1) / GEMM_BM)   // 1563

typedef __attribute__((ext_vector_type(8))) short bf16x8;
typedef __attribute__((ext_vector_type(4))) float f32x4;

__device__ __forceinline__ unsigned short f2bf(float f) {
    unsigned u = __float_as_uint(f);
    unsigned r = u + 0x7fffu + ((u >> 16) & 1u);  // RNE
    return (unsigned short)(r >> 16);
}

// ---------------------------------------------------------------------------
// K1: count (blocks 0..255)  ∥  wtrans (blocks 256..383)
// ---------------------------------------------------------------------------
__global__ __launch_bounds__(256) void count_wtrans_kernel(const int* __restrict__ rowi,
                                                           int* __restrict__ counts,
                                                           const float* __restrict__ w,
                                                           unsigned short* __restrict__ wt) {
    const int tid = threadIdx.x;
    if (blockIdx.x >= NCHUNK) {
        int c = blockIdx.x - NCHUNK;  // 0..127
        wt[c * IN_F + tid] = f2bf(w[tid * OUT_F + c]);
        return;
    }
    __shared__ int hist[NBUCK];
    const int c = blockIdx.x;
    for (int i = tid; i < NBUCK; i += 256) hist[i] = 0;
    __syncthreads();
    const int e0 = c * CHUNK_E;
    for (int i = tid; i < CHUNK_E; i += 256)
        atomicAdd(&hist[rowi[e0 + i] >> 8], 1);
    __syncthreads();
    for (int i = tid; i < NBUCK; i += 256) counts[i * NCHUNK + c] = hist[i];
}

// ---------------------------------------------------------------------------
// K2: scan1 — per-block (4096 elems) exclusive scan in place + block sums.
// ---------------------------------------------------------------------------
__global__ __launch_bounds__(256) void scan1_kernel(int* __restrict__ data,
                                                    int* __restrict__ blocksums,
                                                    int n) {
    __shared__ int sdata[256];
    const int tid = threadIdx.x;
    const int base = blockIdx.x * SCAN_BLK + tid * 16;
    int v[16];
    if (base < n) {
#pragma unroll
        for (int q = 0; q < 4; ++q) {
            int4 t = *reinterpret_cast<const int4*>(&data[base + q * 4]);
            v[q * 4 + 0] = t.x; v[q * 4 + 1] = t.y; v[q * 4 + 2] = t.z; v[q * 4 + 3] = t.w;
        }
    } else {
#pragma unroll
        for (int i = 0; i < 16; ++i) v[i] = 0;
    }
    int pre[16], run = 0;
#pragma unroll
    for (int i = 0; i < 16; ++i) { pre[i] = run; run += v[i]; }
    sdata[tid] = run;
    __syncthreads();
#pragma unroll
    for (int off = 1; off < 256; off <<= 1) {
        int t = (tid >= off) ? sdata[tid - off] : 0;
        __syncthreads();
        sdata[tid] += t;
        __syncthreads();
    }
    int excl = (tid == 0) ? 0 : sdata[tid - 1];
    if (base < n) {
#pragma unroll
        for (int q = 0; q < 4; ++q) {
            int4 t = {excl + pre[q * 4 + 0], excl + pre[q * 4 + 1],
                      excl + pre[q * 4 + 2], excl + pre[q * 4 + 3]};
            *reinterpret_cast<int4*>(&data[base + q * 4]) = t;
        }
    }
    if (tid == 255) blocksums[blockIdx.x] = sdata[255];
}

// ---------------------------------------------------------------------------
// K3: scan2 — single block exclusive scan of nblk (<=256) block sums.
// ---------------------------------------------------------------------------
__global__ __launch_bounds__(256) void scan2_kernel(int* __restrict__ blocksums, int nblk) {
    __shared__ int sdata[256];
    const int tid = threadIdx.x;
    sdata[tid] = (tid < nblk) ? blocksums[tid] : 0;
    __syncthreads();
#pragma unroll
    for (int off = 1; off < 256; off <<= 1) {
        int t = (tid >= off) ? sdata[tid - off] : 0;
        __syncthreads();
        sdata[tid] += t;
        __syncthreads();
    }
    if (tid < nblk) blocksums[tid] = (tid == 0) ? 0 : sdata[tid - 1];
}

// ---------------------------------------------------------------------------
// K4: scatter1 (blocks 0..255)  ∥  gemm (blocks 256..1818)
// gemm: 64x128 tile, BK=32; simple staging (round-9 proven, 68 VGPR),
// doubled block count for TLP-based latency hiding.
// ---------------------------------------------------------------------------
__global__ __launch_bounds__(256) void gemm_scatter_kernel(const float* __restrict__ x,
                                                           const unsigned short* __restrict__ wt,
                                                           unsigned short* __restrict__ support,
                                                           const int* __restrict__ rowi,
                                                           const int* __restrict__ coli,
                                                           const float* __restrict__ val,
                                                           const int* __restrict__ counts,
                                                           const int* __restrict__ blocksums,
                                                           uint2* __restrict__ tmp) {
    const int tid = threadIdx.x;

    if (blockIdx.x < NCHUNK) {
        // ----- scatter1 -----
        __shared__ int cur[NBUCK];
        const int c = blockIdx.x;
        for (int i = tid; i < NBUCK; i += 256) {
            int j = i * NCHUNK + c;
            cur[i] = counts[j] + blocksums[j >> 12];
        }
        __syncthreads();
        const int e0 = c * CHUNK_E;
        for (int i = tid; i < CHUNK_E; i += 256) {
            int e = e0 + i;
            int dst = rowi[e];
            int b = dst >> 8;
            int pos = atomicAdd(&cur[b], 1);
            tmp[pos] = make_uint2(((unsigned)(dst & 255) << 17) | (unsigned)coli[e],
                                  __float_as_uint(val[e]));
        }
        return;
    }

    // ----- gemm: 64-row tile -----
    __shared__ unsigned short xs[GEMM_BM * LDK];  // 64 rows x 32k bf16, stride 40
    __shared__ unsigned short ws[128 * LDK];      // 128 cols x 32k bf16, stride 40

    const int lane = tid & 63;
    const int wv = tid >> 6;
    const int wr = (wv >> 1) * 32;  // wave row offset: 0 / 32
    const int wc = (wv & 1) * 64;   // wave col offset: 0 / 64
    const int row0 = (blockIdx.x - NCHUNK) * GEMM_BM;
    const int l15 = lane & 15;
    const int kg = (lane >> 4) * 8;

    f32x4 acc[2][4];
#pragma unroll
    for (int m = 0; m < 2; ++m)
#pragma unroll
        for (int n = 0; n < 4; ++n) acc[m][n] = (f32x4){0.f, 0.f, 0.f, 0.f};

    for (int kt = 0; kt < 8; ++kt) {
        __syncthreads();
        // stage x tile: 64 rows x 32 k (2 float4 chunks/thread)
#pragma unroll
        for (int i = 0; i < 2; ++i) {
            int idx = tid + 256 * i;  // 0..511
            int r = idx >> 3, q = idx & 7;
            int grow = row0 + r;
            if (grow > N_NODES - 1) grow = N_NODES - 1;
            float4 v = *reinterpret_cast<const float4*>(&x[(size_t)grow * IN_F + kt * 32 + q * 4]);
            ushort4 b;
            b.x = f2bf(v.x); b.y = f2bf(v.y); b.z = f2bf(v.z); b.w = f2bf(v.w);
            *reinterpret_cast<ushort4*>(&xs[r * LDK + q * 4]) = b;
        }
        // stage wT tile: 128 cols x 32 k (2 uint4 chunks/thread)
#pragma unroll
        for (int j = 0; j < 2; ++j) {
            int idx = tid + 256 * j;  // 0..511
            int c = idx >> 2, q = idx & 3;
            uint4 v = *reinterpret_cast<const uint4*>(&wt[c * IN_F + kt * 32 + q * 8]);
            *reinterpret_cast<uint4*>(&ws[c * LDK + q * 8]) = v;
        }
        __syncthreads();

        bf16x8 af[2], bfr[4];
#pragma unroll
        for (int m = 0; m < 2; ++m)
            af[m] = *reinterpret_cast<const bf16x8*>(&xs[(wr + m * 16 + l15) * LDK + kg]);
#pragma unroll
        for (int n = 0; n < 4; ++n)
            bfr[n] = *reinterpret_cast<const bf16x8*>(&ws[(wc + n * 16 + l15) * LDK + kg]);
#pragma unroll
        for (int m = 0; m < 2; ++m)
#pragma unroll
            for (int n = 0; n < 4; ++n)
                acc[m][n] = __builtin_amdgcn_mfma_f32_16x16x32_bf16(af[m], bfr[n], acc[m][n], 0, 0, 0);
    }

#pragma unroll
    for (int m = 0; m < 2; ++m) {
#pragma unroll
        for (int r = 0; r < 4; ++r) {
            int row = row0 + wr + m * 16 + (lane >> 4) * 4 + r;
            if (row < N_NODES) {
#pragma unroll
                for (int n = 0; n < 4; ++n) {
                    support[(size_t)row * OUT_F + wc + n * 16 + l15] = f2bf(acc[m][n][r]);
                }
            }
        }
    }
}

// ---------------------------------------------------------------------------
// K5: fine sort within one 256-node bucket; writes per-node end offsets.
// ---------------------------------------------------------------------------
__global__ __launch_bounds__(256) void fine_kernel(const uint2* __restrict__ tmp,
                                                   const int* __restrict__ counts,
                                                   const int* __restrict__ blocksums,
                                                   uint2* __restrict__ pairs,
                                                   int* __restrict__ offsets) {
    __shared__ int hist[256];
    __shared__ int scanb[256];
    __shared__ int cur[256];
    const int tid = threadIdx.x, b = blockIdx.x;
    int j0 = b * NCHUNK;
    const int start = counts[j0] + blocksums[j0 >> 12];
    int end;
    if (b == NBUCK - 1) end = N_EDGES;
    else {
        int j1 = (b + 1) * NCHUNK;
        end = counts[j1] + blocksums[j1 >> 12];
    }

    hist[tid] = 0;
    __syncthreads();
    for (int i = start + tid; i < end; i += 256)
        atomicAdd(&hist[tmp[i].x >> 17], 1);
    __syncthreads();
    int h = hist[tid];
    scanb[tid] = h;
    __syncthreads();
#pragma unroll
    for (int off = 1; off < 256; off <<= 1) {
        int t = (tid >= off) ? scanb[tid - off] : 0;
        __syncthreads();
        scanb[tid] += t;
        __syncthreads();
    }
    cur[tid] = start + scanb[tid] - h;
    int node = (b << 8) + tid;
    if (node < N_NODES) offsets[node] = start + scanb[tid];
    __syncthreads();
    for (int i = start + tid; i < end; i += 256) {
        uint2 u = tmp[i];
        int dl = u.x >> 17;
        int pos = atomicAdd(&cur[dl], 1);
        pairs[pos] = make_uint2(u.x & 0x1FFFFu, u.y);
    }
}

// ---------------------------------------------------------------------------
// K6: accumulate: one wave64 per node, 4 edge slots x 16 lanes (8 feats each),
// x2 unroll -> 8 gathers in flight per wave. (round-6 proven)
// ---------------------------------------------------------------------------
__global__ __launch_bounds__(256) void accum_kernel(const unsigned short* __restrict__ support,
                                                    const uint2* __restrict__ pairs,
                                                    const int* __restrict__ offsets,
                                                    const float* __restrict__ bias,
                                                    float* __restrict__ out) {
    const int node = blockIdx.x * 4 + (threadIdx.x >> 6);
    const int lane = threadIdx.x & 63;
    const int grp = lane >> 4;   // edge slot 0..3
    const int l16 = lane & 15;   // feats l16*8 .. l16*8+7
    if (node >= N_NODES) return;

    const int start = (node == 0) ? 0 : offsets[node - 1];
    const int end = offsets[node];

    float acc[8];
#pragma unroll
    for (int t = 0; t < 8; ++t) acc[t] = 0.f;

    int j = start + grp;
    for (; j + 4 < end; j += 8) {
        uint2 p0 = pairs[j];
        uint2 p1 = pairs[j + 4];
        uint4 s0 = *reinterpret_cast<const uint4*>(&support[(size_t)p0.x * OUT_F + l16 * 8]);
        uint4 s1 = *reinterpret_cast<const uint4*>(&support[(size_t)p1.x * OUT_F + l16 * 8]);
        float v0 = __uint_as_float(p0.y);
        float v1 = __uint_as_float(p1.y);
        unsigned u0[4] = {s0.x, s0.y, s0.z, s0.w};
        unsigned u1[4] = {s1.x, s1.y, s1.z, s1.w};
#pragma unroll
        for (int q = 0; q < 4; ++q) {
            acc[2 * q + 0] += __uint_as_float(u0[q] << 16) * v0;
            acc[2 * q + 1] += __uint_as_float(u0[q] & 0xffff0000u) * v0;
            acc[2 * q + 0] += __uint_as_float(u1[q] << 16) * v1;
            acc[2 * q + 1] += __uint_as_float(u1[q] & 0xffff0000u) * v1;
        }
    }
    for (; j < end; j += 4) {
        uint2 p0 = pairs[j];
        uint4 s0 = *reinterpret_cast<const uint4*>(&support[(size_t)p0.x * OUT_F + l16 * 8]);
        float v0 = __uint_as_float(p0.y);
        unsigned u0[4] = {s0.x, s0.y, s0.z, s0.w};
#pragma unroll
        for (int q = 0; q < 4; ++q) {
            acc[2 * q + 0] += __uint_as_float(u0[q] << 16) * v0;
            acc[2 * q + 1] += __uint_as_float(u0[q] & 0xffff0000u) * v0;
        }
    }

#pragma unroll
    for (int t = 0; t < 8; ++t) {
        acc[t] += __shfl_xor(acc[t], 16);
        acc[t] += __shfl_xor(acc[t], 32);
    }

    if (grp == 0) {
        float4 b0 = *reinterpret_cast<const float4*>(&bias[l16 * 8]);
        float4 b1 = *reinterpret_cast<const float4*>(&bias[l16 * 8 + 4]);
        f32x4 o0 = {acc[0] + b0.x, acc[1] + b0.y, acc[2] + b0.z, acc[3] + b0.w};
        f32x4 o1 = {acc[4] + b1.x, acc[5] + b1.y, acc[6] + b1.z, acc[7] + b1.w};
        f32x4* op = reinterpret_cast<f32x4*>(&out[(size_t)node * OUT_F + l16 * 8]);
        __builtin_nontemporal_store(o0, op);
        __builtin_nontemporal_store(o1, op + 1);
    }
}

extern "C" void kernel_launch(void* const* d_in, const int* in_sizes, int n_in,
                              void* d_out, int out_size, void* d_ws, size_t ws_size,
                              hipStream_t stream) {
    const float* x       = (const float*)d_in[0];
    const float* weight  = (const float*)d_in[1];
    const float* bias    = (const float*)d_in[2];
    const float* adj_val = (const float*)d_in[3];
    const int*   adj_row = (const int*)d_in[4];
    const int*   adj_col = (const int*)d_in[5];
    float* out = (float*)d_out;

    unsigned short* support = (unsigned short*)d_ws;
    unsigned short* wt = support + (size_t)N_NODES * OUT_F;
    int* counts = (int*)(wt + IN_F * OUT_F);
    int* blocksums = counts + NSCAN;
    int* offsets = blocksums + 32;
    uint2* tmp = (uint2*)(offsets + 100000);
    uint2* pairs = tmp + N_EDGES;

    // K1: count ∥ wtrans
    count_wtrans_kernel<<<NCHUNK + OUT_F, 256, 0, stream>>>(adj_row, counts, weight, wt);
    // K2/K3: scan
    scan1_kernel<<<NSCAN_BLOCKS, 256, 0, stream>>>(counts, blocksums, NSCAN);
    scan2_kernel<<<1, 256, 0, stream>>>(blocksums, NSCAN_BLOCKS);
    // K4: scatter1 ∥ gemm (64-row tiles)
    gemm_scatter_kernel<<<NCHUNK + GEMM_BLOCKS, 256, 0, stream>>>(
        x, wt, support, adj_row, adj_col, adj_val, counts, blocksums, tmp);
    // K5: fine sort per bucket
    fine_kernel<<<NBUCK, 256, 0, stream>>>(tmp, counts, blocksums, pairs, offsets);
    // K6: accumulate per destination node
    accum_kernel<<<(N_NODES + 3) / 4, 256, 0, stream>>>(support, pairs, offsets, bias, out);
}

// Round 12
// 132.919 us; speedup vs baseline: 1.1352x; 1.0282x over previous
//
#include <hip/hip_runtime.h>

#define N_NODES 100000
#define N_EDGES 1600000
#define IN_F 256
#define OUT_F 128

// two-level counting sort params
#define NBUCK 391            // ceil(N_NODES / 256): coarse bucket = dst >> 8
#define NCHUNK 256           // edge chunks
#define CHUNK_E (N_EDGES / NCHUNK)  // 6250
#define NSCAN (NBUCK * NCHUNK)      // 100096 count-matrix entries (mult of 16)
#define SCAN_BLK 4096        // elems per scan1 block
#define NSCAN_BLOCKS ((NSCAN + SCAN_BLK - 1) / SCAN_BLK)  // 25

#define GEMM_BM 64
#define GEMM_BLOCKS ((N_NODES + GEMM_BM - 1) / GEMM_BM)   // 1563

typedef __attribute__((ext_vector_type(8))) short bf16x8;
typedef __attribute__((ext_vector_type(4))) float f32x4;

typedef const __attribute__((address_space(1))) unsigned int* gas_u32;
typedef __attribute__((address_space(3))) unsigned int* las_u32;

__device__ __forceinline__ unsigned short f2bf(float f) {
    unsigned u = __float_as_uint(f);
    unsigned r = u + 0x7fffu + ((u >> 16) & 1u);  // RNE
    return (unsigned short)(r >> 16);
}

// ---------------------------------------------------------------------------
// K1: count (blocks 0..255)  ∥  wtrans (blocks 256..383)
// ---------------------------------------------------------------------------
__global__ __launch_bounds__(256) void count_wtrans_kernel(const int* __restrict__ rowi,
                                                           int* __restrict__ counts,
                                                           const float* __restrict__ w,
                                                           unsigned short* __restrict__ wt) {
    const int tid = threadIdx.x;
    if (blockIdx.x >= NCHUNK) {
        int c = blockIdx.x - NCHUNK;  // 0..127
        wt[c * IN_F + tid] = f2bf(w[tid * OUT_F + c]);
        return;
    }
    __shared__ int hist[NBUCK];
    const int c = blockIdx.x;
    for (int i = tid; i < NBUCK; i += 256) hist[i] = 0;
    __syncthreads();
    const int e0 = c * CHUNK_E;
    for (int i = tid; i < CHUNK_E; i += 256)
        atomicAdd(&hist[rowi[e0 + i] >> 8], 1);
    __syncthreads();
    for (int i = tid; i < NBUCK; i += 256) counts[i * NCHUNK + c] = hist[i];
}

// ---------------------------------------------------------------------------
// K2: scan1 — per-block (4096 elems) exclusive scan in place + block sums.
// ---------------------------------------------------------------------------
__global__ __launch_bounds__(256) void scan1_kernel(int* __restrict__ data,
                                                    int* __restrict__ blocksums,
                                                    int n) {
    __shared__ int sdata[256];
    const int tid = threadIdx.x;
    const int base = blockIdx.x * SCAN_BLK + tid * 16;
    int v[16];
    if (base < n) {
#pragma unroll
        for (int q = 0; q < 4; ++q) {
            int4 t = *reinterpret_cast<const int4*>(&data[base + q * 4]);
            v[q * 4 + 0] = t.x; v[q * 4 + 1] = t.y; v[q * 4 + 2] = t.z; v[q * 4 + 3] = t.w;
        }
    } else {
#pragma unroll
        for (int i = 0; i < 16; ++i) v[i] = 0;
    }
    int pre[16], run = 0;
#pragma unroll
    for (int i = 0; i < 16; ++i) { pre[i] = run; run += v[i]; }
    sdata[tid] = run;
    __syncthreads();
#pragma unroll
    for (int off = 1; off < 256; off <<= 1) {
        int t = (tid >= off) ? sdata[tid - off] : 0;
        __syncthreads();
        sdata[tid] += t;
        __syncthreads();
    }
    int excl = (tid == 0) ? 0 : sdata[tid - 1];
    if (base < n) {
#pragma unroll
        for (int q = 0; q < 4; ++q) {
            int4 t = {excl + pre[q * 4 + 0], excl + pre[q * 4 + 1],
                      excl + pre[q * 4 + 2], excl + pre[q * 4 + 3]};
            *reinterpret_cast<int4*>(&data[base + q * 4]) = t;
        }
    }
    if (tid == 255) blocksums[blockIdx.x] = sdata[255];
}

// ---------------------------------------------------------------------------
// K3: scan2 — single block exclusive scan of nblk (<=256) block sums.
// ---------------------------------------------------------------------------
__global__ __launch_bounds__(256) void scan2_kernel(int* __restrict__ blocksums, int nblk) {
    __shared__ int sdata[256];
    const int tid = threadIdx.x;
    sdata[tid] = (tid < nblk) ? blocksums[tid] : 0;
    __syncthreads();
#pragma unroll
    for (int off = 1; off < 256; off <<= 1) {
        int t = (tid >= off) ? sdata[tid - off] : 0;
        __syncthreads();
        sdata[tid] += t;
        __syncthreads();
    }
    if (tid < nblk) blocksums[tid] = (tid == 0) ? 0 : sdata[tid - 1];
}

// ---------------------------------------------------------------------------
// K4: scatter1 (blocks 0..255)  ∥  gemm (blocks 256..1818)
// gemm: 64x128 tile, BK=32. Staging via global_load_lds (width 16, async DMA):
// w as bf16 direct; x as f32, converted to bf16 at fragment-read time.
// LDS dest is linear (DMA requirement); bank conflicts on ds_read fixed by
// pre-swizzling the GLOBAL source chunk index (same involution on read side):
//   x: chunk c' = c ^ (r&7)      (8x 16B chunks per 64-row x 32k f32 row)
//   w: chunk q' = q ^ ((col>>1)&3) (4x 16B chunks per col's 32k bf16)
// ---------------------------------------------------------------------------
__global__ __launch_bounds__(256) void gemm_scatter_kernel(const float* __restrict__ x,
                                                           const unsigned short* __restrict__ wt,
                                                           unsigned short* __restrict__ support,
                                                           const int* __restrict__ rowi,
                                                           const int* __restrict__ coli,
                                                           const float* __restrict__ val,
                                                           const int* __restrict__ counts,
                                                           const int* __restrict__ blocksums,
                                                           uint2* __restrict__ tmp) {
    const int tid = threadIdx.x;

    if (blockIdx.x < NCHUNK) {
        // ----- scatter1 -----
        __shared__ int cur[NBUCK];
        const int c = blockIdx.x;
        for (int i = tid; i < NBUCK; i += 256) {
            int j = i * NCHUNK + c;
            cur[i] = counts[j] + blocksums[j >> 12];
        }
        __syncthreads();
        const int e0 = c * CHUNK_E;
        for (int i = tid; i < CHUNK_E; i += 256) {
            int e = e0 + i;
            int dst = rowi[e];
            int b = dst >> 8;
            int pos = atomicAdd(&cur[b], 1);
            tmp[pos] = make_uint2(((unsigned)(dst & 255) << 17) | (unsigned)coli[e],
                                  __float_as_uint(val[e]));
        }
        return;
    }

    // ----- gemm -----
    __shared__ float xs[GEMM_BM * 32];          // 8 KB, [row][swizzled 16B chunk]
    __shared__ unsigned short ws[128 * 32];     // 8 KB, [col][swizzled 16B chunk]

    const int lane = tid & 63;
    const int wv = tid >> 6;
    const int wr = (wv >> 1) * 32;  // wave row offset: 0 / 32
    const int wc = (wv & 1) * 64;   // wave col offset: 0 / 64
    const int row0 = (blockIdx.x - NCHUNK) * GEMM_BM;
    const int l15 = lane & 15;
    const int kq = lane >> 4;       // k-quarter 0..3

    // staging sources (advance by +kt*32 elems each k-step); LDS dests linear
    const float* xg[2];
    float* xl[2];
#pragma unroll
    for (int i = 0; i < 2; ++i) {
        int idx = tid + 256 * i;        // 0..511
        int r = idx >> 3, c = idx & 7;  // row, 16B-chunk
        int grow = row0 + r;
        if (grow > N_NODES - 1) grow = N_NODES - 1;
        xg[i] = &x[(size_t)grow * IN_F + ((c ^ (r & 7)) << 2)];
        xl[i] = &xs[idx * 4];
    }
    const unsigned short* wg[2];
    unsigned short* wl[2];
#pragma unroll
    for (int j = 0; j < 2; ++j) {
        int idx = tid + 256 * j;        // 0..511
        int col = idx >> 2, q = idx & 3;
        wg[j] = &wt[col * IN_F + ((q ^ ((col >> 1) & 3)) << 3)];
        wl[j] = &ws[idx * 8];
    }

    f32x4 acc[2][4];
#pragma unroll
    for (int m = 0; m < 2; ++m)
#pragma unroll
        for (int n = 0; n < 4; ++n) acc[m][n] = (f32x4){0.f, 0.f, 0.f, 0.f};

    for (int kt = 0; kt < 8; ++kt) {
        __syncthreads();  // previous tile fully consumed
#pragma unroll
        for (int i = 0; i < 2; ++i)
            __builtin_amdgcn_global_load_lds((gas_u32)(xg[i] + kt * 32),
                                             (las_u32)xl[i], 16, 0, 0);
#pragma unroll
        for (int j = 0; j < 2; ++j)
            __builtin_amdgcn_global_load_lds((gas_u32)(wg[j] + kt * 32),
                                             (las_u32)wl[j], 16, 0, 0);
        __syncthreads();  // drains vmcnt -> tile ready

        bf16x8 af[2], bfr[4];
#pragma unroll
        for (int m = 0; m < 2; ++m) {
            int rl = wr + m * 16 + l15;
            int s0 = (2 * kq) ^ (rl & 7);
            int s1 = (2 * kq + 1) ^ (rl & 7);
            f32x4 a0 = *reinterpret_cast<const f32x4*>(&xs[(rl * 8 + s0) * 4]);
            f32x4 a1 = *reinterpret_cast<const f32x4*>(&xs[(rl * 8 + s1) * 4]);
            bf16x8 t;
            t[0] = (short)f2bf(a0[0]); t[1] = (short)f2bf(a0[1]);
            t[2] = (short)f2bf(a0[2]); t[3] = (short)f2bf(a0[3]);
            t[4] = (short)f2bf(a1[0]); t[5] = (short)f2bf(a1[1]);
            t[6] = (short)f2bf(a1[2]); t[7] = (short)f2bf(a1[3]);
            af[m] = t;
        }
#pragma unroll
        for (int n = 0; n < 4; ++n) {
            int cl = wc + n * 16 + l15;
            int slot = kq ^ ((cl >> 1) & 3);
            bfr[n] = *reinterpret_cast<const bf16x8*>(&ws[(cl * 4 + slot) * 8]);
        }
#pragma unroll
        for (int m = 0; m < 2; ++m)
#pragma unroll
            for (int n = 0; n < 4; ++n)
                acc[m][n] = __builtin_amdgcn_mfma_f32_16x16x32_bf16(af[m], bfr[n], acc[m][n], 0, 0, 0);
    }

#pragma unroll
    for (int m = 0; m < 2; ++m) {
#pragma unroll
        for (int r = 0; r < 4; ++r) {
            int row = row0 + wr + m * 16 + (lane >> 4) * 4 + r;
            if (row < N_NODES) {
#pragma unroll
                for (int n = 0; n < 4; ++n) {
                    support[(size_t)row * OUT_F + wc + n * 16 + l15] = f2bf(acc[m][n][r]);
                }
            }
        }
    }
}

// ---------------------------------------------------------------------------
// K5: fine sort within one 256-node bucket; writes per-node end offsets.
// ---------------------------------------------------------------------------
__global__ __launch_bounds__(256) void fine_kernel(const uint2* __restrict__ tmp,
                                                   const int* __restrict__ counts,
                                                   const int* __restrict__ blocksums,
                                                   uint2* __restrict__ pairs,
                                                   int* __restrict__ offsets) {
    __shared__ int hist[256];
    __shared__ int scanb[256];
    __shared__ int cur[256];
    const int tid = threadIdx.x, b = blockIdx.x;
    int j0 = b * NCHUNK;
    const int start = counts[j0] + blocksums[j0 >> 12];
    int end;
    if (b == NBUCK - 1) end = N_EDGES;
    else {
        int j1 = (b + 1) * NCHUNK;
        end = counts[j1] + blocksums[j1 >> 12];
    }

    hist[tid] = 0;
    __syncthreads();
    for (int i = start + tid; i < end; i += 256)
        atomicAdd(&hist[tmp[i].x >> 17], 1);
    __syncthreads();
    int h = hist[tid];
    scanb[tid] = h;
    __syncthreads();
#pragma unroll
    for (int off = 1; off < 256; off <<= 1) {
        int t = (tid >= off) ? scanb[tid - off] : 0;
        __syncthreads();
        scanb[tid] += t;
        __syncthreads();
    }
    cur[tid] = start + scanb[tid] - h;
    int node = (b << 8) + tid;
    if (node < N_NODES) offsets[node] = start + scanb[tid];
    __syncthreads();
    for (int i = start + tid; i < end; i += 256) {
        uint2 u = tmp[i];
        int dl = u.x >> 17;
        int pos = atomicAdd(&cur[dl], 1);
        pairs[pos] = make_uint2(u.x & 0x1FFFFu, u.y);
    }
}

// ---------------------------------------------------------------------------
// K6: accumulate: one wave64 per node, 4 edge slots x 16 lanes (8 feats each),
// x2 unroll -> 8 gathers in flight per wave. (round-6 proven)
// ---------------------------------------------------------------------------
__global__ __launch_bounds__(256) void accum_kernel(const unsigned short* __restrict__ support,
                                                    const uint2* __restrict__ pairs,
                                                    const int* __restrict__ offsets,
                                                    const float* __restrict__ bias,
                                                    float* __restrict__ out) {
    const int node = blockIdx.x * 4 + (threadIdx.x >> 6);
    const int lane = threadIdx.x & 63;
    const int grp = lane >> 4;   // edge slot 0..3
    const int l16 = lane & 15;   // feats l16*8 .. l16*8+7
    if (node >= N_NODES) return;

    const int start = (node == 0) ? 0 : offsets[node - 1];
    const int end = offsets[node];

    float acc[8];
#pragma unroll
    for (int t = 0; t < 8; ++t) acc[t] = 0.f;

    int j = start + grp;
    for (; j + 4 < end; j += 8) {
        uint2 p0 = pairs[j];
        uint2 p1 = pairs[j + 4];
        uint4 s0 = *reinterpret_cast<const uint4*>(&support[(size_t)p0.x * OUT_F + l16 * 8]);
        uint4 s1 = *reinterpret_cast<const uint4*>(&support[(size_t)p1.x * OUT_F + l16 * 8]);
        float v0 = __uint_as_float(p0.y);
        float v1 = __uint_as_float(p1.y);
        unsigned u0[4] = {s0.x, s0.y, s0.z, s0.w};
        unsigned u1[4] = {s1.x, s1.y, s1.z, s1.w};
#pragma unroll
        for (int q = 0; q < 4; ++q) {
            acc[2 * q + 0] += __uint_as_float(u0[q] << 16) * v0;
            acc[2 * q + 1] += __uint_as_float(u0[q] & 0xffff0000u) * v0;
            acc[2 * q + 0] += __uint_as_float(u1[q] << 16) * v1;
            acc[2 * q + 1] += __uint_as_float(u1[q] & 0xffff0000u) * v1;
        }
    }
    for (; j < end; j += 4) {
        uint2 p0 = pairs[j];
        uint4 s0 = *reinterpret_cast<const uint4*>(&support[(size_t)p0.x * OUT_F + l16 * 8]);
        float v0 = __uint_as_float(p0.y);
        unsigned u0[4] = {s0.x, s0.y, s0.z, s0.w};
#pragma unroll
        for (int q = 0; q < 4; ++q) {
            acc[2 * q + 0] += __uint_as_float(u0[q] << 16) * v0;
            acc[2 * q + 1] += __uint_as_float(u0[q] & 0xffff0000u) * v0;
        }
    }

#pragma unroll
    for (int t = 0; t < 8; ++t) {
        acc[t] += __shfl_xor(acc[t], 16);
        acc[t] += __shfl_xor(acc[t], 32);
    }

    if (grp == 0) {
        float4 b0 = *reinterpret_cast<const float4*>(&bias[l16 * 8]);
        float4 b1 = *reinterpret_cast<const float4*>(&bias[l16 * 8 + 4]);
        f32x4 o0 = {acc[0] + b0.x, acc[1] + b0.y, acc[2] + b0.z, acc[3] + b0.w};
        f32x4 o1 = {acc[4] + b1.x, acc[5] + b1.y, acc[6] + b1.z, acc[7] + b1.w};
        f32x4* op = reinterpret_cast<f32x4*>(&out[(size_t)node * OUT_F + l16 * 8]);
        __builtin_nontemporal_store(o0, op);
        __builtin_nontemporal_store(o1, op + 1);
    }
}

extern "C" void kernel_launch(void* const* d_in, const int* in_sizes, int n_in,
                              void* d_out, int out_size, void* d_ws, size_t ws_size,
                              hipStream_t stream) {
    const float* x       = (const float*)d_in[0];
    const float* weight  = (const float*)d_in[1];
    const float* bias    = (const float*)d_in[2];
    const float* adj_val = (const float*)d_in[3];
    const int*   adj_row = (const int*)d_in[4];
    const int*   adj_col = (const int*)d_in[5];
    float* out = (float*)d_out;

    unsigned short* support = (unsigned short*)d_ws;
    unsigned short* wt = support + (size_t)N_NODES * OUT_F;
    int* counts = (int*)(wt + IN_F * OUT_F);
    int* blocksums = counts + NSCAN;
    int* offsets = blocksums + 32;
    uint2* tmp = (uint2*)(offsets + 100000);
    uint2* pairs = tmp + N_EDGES;

    // K1: count ∥ wtrans
    count_wtrans_kernel<<<NCHUNK + OUT_F, 256, 0, stream>>>(adj_row, counts, weight, wt);
    // K2/K3: scan
    scan1_kernel<<<NSCAN_BLOCKS, 256, 0, stream>>>(counts, blocksums, NSCAN);
    scan2_kernel<<<1, 256, 0, stream>>>(blocksums, NSCAN_BLOCKS);
    // K4: scatter1 ∥ gemm (global_load_lds staging)
    gemm_scatter_kernel<<<NCHUNK + GEMM_BLOCKS, 256, 0, stream>>>(
        x, wt, support, adj_row, adj_col, adj_val, counts, blocksums, tmp);
    // K5: fine sort per bucket
    fine_kernel<<<NBUCK, 256, 0, stream>>>(tmp, counts, blocksums, pairs, offsets);
    // K6: accumulate per destination node
    accum_kernel<<<(N_NODES + 3) / 4, 256, 0, stream>>>(support, pairs, offsets, bias, out);
}